// Round 8
// baseline (221.360 us; speedup 1.0000x reference)
//
#include <hip/hip_runtime.h>
#include <hip/hip_bf16.h>
#include <hip/hip_fp16.h>
#include <stdint.h>

#define B_SIZE 8192
#define D_SIZE 2048
#define C_SIZE 128
#define N_INNER 255
#define N_LEAF 256
#define NPAD 256
#define NBLK_PATH 2048   // one row per wave, 4 waves/block

typedef _Float16 half8 __attribute__((ext_vector_type(8)));
typedef __fp16 pk16x2 __attribute__((ext_vector_type(2)));   // return type of cvt_pkrtz
typedef float f32x4 __attribute__((ext_vector_type(4)));
typedef unsigned short u16;

// ---- fp32 -> (hi,lo) fp16 split, packed pairs ----
__device__ inline uint32_t pkh(float a, float b) {
    pk16x2 h = __builtin_amdgcn_cvt_pkrtz(a, b);
    return __builtin_bit_cast(uint32_t, h);
}
__device__ inline void split4(const float4 v, uint2& hi, uint2& lo) {
    pk16x2 a01 = __builtin_amdgcn_cvt_pkrtz(v.x, v.y);
    pk16x2 a23 = __builtin_amdgcn_cvt_pkrtz(v.z, v.w);
    float r0 = v.x - (float)a01[0];
    float r1 = v.y - (float)a01[1];
    float r2 = v.z - (float)a23[0];
    float r3 = v.w - (float)a23[1];
    hi = make_uint2(__builtin_bit_cast(uint32_t, a01), __builtin_bit_cast(uint32_t, a23));
    lo = make_uint2(pkh(r0, r1), pkh(r2, r3));
}

// ---------------- K-pre (merged): split W -> Wh/Wl, softmax -> Q/logQt, zero gacc ----------------
__global__ __launch_bounds__(256) void prep_kernel(
    const float* __restrict__ Wsrc, u16* __restrict__ Wh, u16* __restrict__ Wl,
    const float* __restrict__ lp, float* __restrict__ Q, float* __restrict__ logQt,
    float* __restrict__ gacc)
{
    int bid = blockIdx.x;
    int t = threadIdx.x;
    if (bid < 256) {
        // W split: row = bid, each thread 8 k
        int row = bid;
        int k = t * 8;
        uint2 h0, l0, h1, l1;
        if (row < N_INNER) {
            float4 v0 = *(const float4*)(Wsrc + (size_t)row * D_SIZE + k);
            float4 v1 = *(const float4*)(Wsrc + (size_t)row * D_SIZE + k + 4);
            split4(v0, h0, l0); split4(v1, h1, l1);
        } else {
            h0 = l0 = h1 = l1 = make_uint2(0u, 0u);
        }
        *(uint2*)&Wh[(size_t)row * D_SIZE + k]     = h0;
        *(uint2*)&Wh[(size_t)row * D_SIZE + k + 4] = h1;
        *(uint2*)&Wl[(size_t)row * D_SIZE + k]     = l0;
        *(uint2*)&Wl[(size_t)row * D_SIZE + k + 4] = l1;
    } else {
        // softmax over leaf row (bid-256); threads 0..127 work, all hit barriers
        int row = bid - 256;
        if (bid == 256) gacc[t] = 0.f;    // zero the global accumulators (256 floats)
        __shared__ float red[128];
        float v = 0.f;
        if (t < 128) { v = lp[row * C_SIZE + t]; red[t] = v; }
        __syncthreads();
        for (int s = 64; s > 0; s >>= 1) { if (t < s) red[t] = fmaxf(red[t], red[t + s]); __syncthreads(); }
        float mx = red[0]; __syncthreads();
        float e = 0.f;
        if (t < 128) { e = expf(v - mx); red[t] = e; }
        __syncthreads();
        for (int s = 64; s > 0; s >>= 1) { if (t < s) red[t] += red[t + s]; __syncthreads(); }
        float sum = red[0];
        if (t < 128) {
            Q[row * C_SIZE + t] = e / sum;
            logQt[(size_t)t * N_LEAF + row] = (v - mx) - logf(sum);   // [class][leaf]
        }
    }
}

// ---------------- K1: z_part[kz] = x @ W^T partials, fp16-split MFMA, BARRIER-FREE ----------------
// FROZEN at the best measured config (R4/R7: ~60 us, VGPR=128, no spill). BM=64, 4 waves x
// 64 cols, BK=32, KSPLIT=4, A via wave-private LDS + lgkm fence, A+B one-deep reg prefetch,
// kz = bid & 3 clusters one kz per XCD under round-robin dispatch (B slice L2-hot).
// NOTE: launch_bounds min-waves MUST stay 2 — (256,4) squeezes arch-VGPR to 64 and
// spills ~1.1 GB scratch (R5: 380 us). Do not raise it.
#define GBM 64
#define GBK 32
#define GKSPLIT 4
#define KCHUNK (D_SIZE / GKSPLIT)   // 512
#define KITERS (KCHUNK / GBK)       // 16
#define LDKA 40                     // padded A row stride in u16 (80 B -> 2-way bank alias = free)

__global__ __launch_bounds__(256, 2) void gemm_mfma(
    const float* __restrict__ x, const u16* __restrict__ Wh, const u16* __restrict__ Wl,
    float* __restrict__ zp)
{
    __shared__ __align__(16) u16 sAh[4][GBM * LDKA];
    __shared__ __align__(16) u16 sAl[4][GBM * LDKA];

    const int t = threadIdx.x;
    const int lane = t & 63, w = t >> 6;
    const int lr = lane & 15, lq = lane >> 4;
    const int mi = blockIdx.x >> 2;          // m-tile index 0..127
    const int kz = blockIdx.x & 3;           // kz clustered per XCD under round-robin
    const int m0 = mi * GBM;
    const int kb0 = kz * KCHUNK;

    f32x4 acc[4][4];
    #pragma unroll
    for (int mt = 0; mt < 4; ++mt)
        #pragma unroll
        for (int nt = 0; nt < 4; ++nt) acc[mt][nt] = (f32x4){0.f, 0.f, 0.f, 0.f};

    // prologue: load first A tile (64 rows x 32 k fp32, 8 float4/lane, coalesced 8 lanes/row)
    float4 av_c[8];
    #pragma unroll
    for (int i = 0; i < 8; ++i) {
        int idx = i * 64 + lane;
        int row = idx >> 3, ch = idx & 7;
        av_c[i] = *(const float4*)(x + (size_t)(m0 + row) * D_SIZE + kb0 + ch * 4);
    }
    // prologue: load kt=0 B fragments
    half8 bh[4], bl[4];
    #pragma unroll
    for (int nt = 0; nt < 4; ++nt) {
        int row = w * 64 + nt * 16 + lr;
        bh[nt] = *(const half8*)(Wh + (size_t)row * D_SIZE + kb0 + lq * 8);
        bl[nt] = *(const half8*)(Wl + (size_t)row * D_SIZE + kb0 + lq * 8);
    }

    #pragma unroll
    for (int kt = 0; kt < KITERS; ++kt) {
        const int kb = kb0 + kt * GBK;
        // 1. issue NEXT kt's B loads (consumed next iteration)
        half8 nbh[4], nbl[4];
        if (kt + 1 < KITERS) {
            #pragma unroll
            for (int nt = 0; nt < 4; ++nt) {
                int row = w * 64 + nt * 16 + lr;
                nbh[nt] = *(const half8*)(Wh + (size_t)row * D_SIZE + kb + GBK + lq * 8);
                nbl[nt] = *(const half8*)(Wl + (size_t)row * D_SIZE + kb + GBK + lq * 8);
            }
        }
        // 2. issue NEXT kt's A loads (consumed next iteration)
        float4 av_n[8];
        if (kt + 1 < KITERS) {
            #pragma unroll
            for (int i = 0; i < 8; ++i) {
                int idx = i * 64 + lane;
                int row = idx >> 3, ch = idx & 7;
                av_n[i] = *(const float4*)(x + (size_t)(m0 + row) * D_SIZE + kb + GBK + ch * 4);
            }
        }
        // 3. split current A into this wave's private LDS region
        #pragma unroll
        for (int i = 0; i < 8; ++i) {
            int idx = i * 64 + lane;
            int row = idx >> 3, ch = idx & 7;
            uint2 hi, lo; split4(av_c[i], hi, lo);
            *(uint2*)&sAh[w][row * LDKA + ch * 4] = hi;
            *(uint2*)&sAl[w][row * LDKA + ch * 4] = lo;
        }
        asm volatile("s_waitcnt lgkmcnt(0)" ::: "memory");  // wave-sync LDS: writes visible to own wave
        // 4. A fragments
        half8 ah[4], al[4];
        #pragma unroll
        for (int mt = 0; mt < 4; ++mt) {
            int off = (mt * 16 + lr) * LDKA + lq * 8;
            ah[mt] = *(const half8*)&sAh[w][off];
            al[mt] = *(const half8*)&sAl[w][off];
        }
        // 5. MFMA (hi*hi + hi*lo + lo*hi)
        #pragma unroll
        for (int mt = 0; mt < 4; ++mt)
            #pragma unroll
            for (int nt = 0; nt < 4; ++nt) {
                acc[mt][nt] = __builtin_amdgcn_mfma_f32_16x16x32_f16(ah[mt], bh[nt], acc[mt][nt], 0, 0, 0);
                acc[mt][nt] = __builtin_amdgcn_mfma_f32_16x16x32_f16(ah[mt], bl[nt], acc[mt][nt], 0, 0, 0);
                acc[mt][nt] = __builtin_amdgcn_mfma_f32_16x16x32_f16(al[mt], bh[nt], acc[mt][nt], 0, 0, 0);
            }
        // 6. rotate prefetched A and B into current
        if (kt + 1 < KITERS) {
            #pragma unroll
            for (int i = 0; i < 8; ++i) av_c[i] = av_n[i];
            #pragma unroll
            for (int nt = 0; nt < 4; ++nt) { bh[nt] = nbh[nt]; bl[nt] = nbl[nt]; }
        }
    }

    float* zout = zp + (size_t)kz * B_SIZE * NPAD;
    #pragma unroll
    for (int mt = 0; mt < 4; ++mt) {
        #pragma unroll
        for (int nt = 0; nt < 4; ++nt) {
            int gn = w * 64 + nt * 16 + lr;
            #pragma unroll
            for (int r = 0; r < 4; ++r) {
                int gm = m0 + mt * 16 + lq * 4 + r;
                zout[(size_t)gm * NPAD + gn] = acc[mt][nt][r];
            }
        }
    }
}

// ---------------- K2: fused reduce + sigmoid + paths + penalties + loss + argmax gather ----------------
// 2048 blocks x 4 waves x ONE ROW EACH (was 512 x 4 x 4): 8 blocks/CU = max thread
// occupancy, no serial i-loop -> 4x more independent latency chains in flight.
// Block results accumulate into gacc via device fp32 atomics (proven correct in R7).
__global__ __launch_bounds__(256) void path_kernel(
    const float* __restrict__ z, const int* __restrict__ target,
    const float* __restrict__ bvec, const float* __restrict__ beta,
    const float* __restrict__ Q, const float* __restrict__ logQt,
    float* __restrict__ gacc, float* __restrict__ out)
{
    __shared__ float pbuf[4][256];
    __shared__ float s_num[128], s_den[128], s_loss;
    const int t = threadIdx.x, w = t >> 6, lane = t & 63;
    const int c0 = lane * 4;

    if (t < 128) s_num[t] = 0.f;
    else s_den[t - 128] = 0.f;
    if (t == 0) s_loss = 0.f;
    __syncthreads();   // init visible to all waves before end-of-block atomics

    const int r = blockIdx.x * 4 + w;   // one row per wave

    float bet[4], bia[4];
    #pragma unroll
    for (int j = 0; j < 4; ++j) {
        int c = c0 + j;
        bet[j] = (c < N_INNER) ? beta[c] : 0.f;
        bia[j] = (c < N_INNER) ? bvec[c] : 0.f;
    }

    // z partials reduce + sigmoid
    float4 s = make_float4(0.f, 0.f, 0.f, 0.f);
    #pragma unroll
    for (int p = 0; p < GKSPLIT; ++p) {
        float4 v = *(const float4*)(z + ((size_t)p * B_SIZE + r) * NPAD + c0);
        s.x += v.x; s.y += v.y; s.z += v.z; s.w += v.w;
    }
    float zv[4] = {s.x, s.y, s.z, s.w};
    float pv[4];
    #pragma unroll
    for (int j = 0; j < 4; ++j) {
        int c = c0 + j;
        pv[j] = (c < N_INNER) ? 1.f / (1.f + expf(-bet[j] * (zv[j] + bia[j]))) : 0.f;
    }
    *(float4*)&pbuf[w][c0] = make_float4(pv[0], pv[1], pv[2], pv[3]);
    asm volatile("s_waitcnt lgkmcnt(0)" ::: "memory");  // wave-private LDS visibility

    int tg = target[r];
    float4 lq4 = *(const float4*)(logQt + (size_t)tg * N_LEAF + c0);
    float lqa[4] = {lq4.x, lq4.y, lq4.z, lq4.w};

    // ---- leaf path products, factored (bit-identical association order):
    // leaves c0..c0+3 share levels d=0..5; d=6 node common (bit = j>>1);
    // d=7 node = 127 + 2*lane + (j>>1), bit = j&1.
    float P = 1.f;
    #pragma unroll
    for (int d = 0; d < 6; ++d) {
        int node = (1 << d) - 1 + (c0 >> (8 - d));
        int bit = (c0 >> (7 - d)) & 1;
        float pvn = pbuf[w][node];
        P *= bit ? pvn : (1.f - pvn);
    }
    float p6  = pbuf[w][63 + lane];
    float p7a = pbuf[w][127 + 2 * lane];
    float p7b = pbuf[w][127 + 2 * lane + 1];
    float lsum = 0.f, bestV = -1.f;
    int bestI = 0;
    #pragma unroll
    for (int j = 0; j < 4; ++j) {
        float t6 = (j & 2) ? p6 : (1.f - p6);
        float p7 = (j & 2) ? p7b : p7a;
        float t7 = (j & 1) ? p7 : (1.f - p7);
        float pl = (P * t6) * t7;
        lsum += pl * lqa[j];
        if (pl > bestV) { bestV = pl; bestI = c0 + j; }  // ascending j keeps lowest tie
    }

    float pnum[4] = {0.f, 0.f, 0.f, 0.f};
    float pden[4] = {0.f, 0.f, 0.f, 0.f};
    if (lane < 32) {
        #pragma unroll
        for (int j = 0; j < 4; ++j) {
            int c = c0 + j;
            if (c < 127) {
                int h = c + 1; int d = 31 - __clz(h);
                float pp = 1.f;
                for (int e = 0; e < d; ++e) {
                    int ha = h >> (d - e);
                    int bit = (h >> (d - 1 - e)) & 1;
                    float pvn = pbuf[w][ha - 1];
                    pp *= bit ? pvn : (1.f - pvn);
                }
                pnum[j] = pbuf[w][c] * pp;
                pden[j] = pp;
            }
        }
    }

    #pragma unroll
    for (int m = 1; m < 64; m <<= 1) {
        lsum += __shfl_xor(lsum, m, 64);
        float ov = __shfl_xor(bestV, m, 64);
        int   oi = __shfl_xor(bestI, m, 64);
        if (ov > bestV || (ov == bestV && oi < bestI)) { bestV = ov; bestI = oi; }
    }
    out[1 + (size_t)r * C_SIZE + lane]      = Q[bestI * C_SIZE + lane];
    out[1 + (size_t)r * C_SIZE + lane + 64] = Q[bestI * C_SIZE + lane + 64];

    // block-level reduction via LDS atomics, then one global atomic per column (255/block)
    if (lane < 32) {
        #pragma unroll
        for (int j = 0; j < 4; ++j) {
            int c = c0 + j;
            if (c < 127) {
                atomicAdd(&s_num[c], pnum[j]);
                atomicAdd(&s_den[c], pden[j]);
            }
        }
    }
    if (lane == 0) atomicAdd(&s_loss, lsum);
    __syncthreads();
    // gacc layout: [0..126] num, [127] loss, [128..254] den
    if (t < 127)        atomicAdd(&gacc[t], s_num[t]);
    else if (t == 127)  atomicAdd(&gacc[127], s_loss);
    else if (t < 255)   atomicAdd(&gacc[t], s_den[t - 128]);
}

// ---------------- K3: finalize total from gacc (1 block, trivial) ----------------
__global__ __launch_bounds__(256) void finalize_kernel(
    const float* __restrict__ gacc, float* __restrict__ out)
{
    __shared__ float fs[256];
    __shared__ float fred[128];
    int t = threadIdx.x;
    fs[t] = (t < 255) ? gacc[t] : 0.f;
    __syncthreads();
    float term = 0.f;
    if (t < 127) {
        int d = 31 - __clz(t + 1);
        float lam = 0.1f * exp2f(-(float)(d + 1));
        float pen = fs[t] / fs[128 + t];
        term = lam * 0.5f * (logf(pen) + logf(1.f - pen));
    }
    if (t < 128) { fred[t] = term; }
    __syncthreads();
    for (int sh = 64; sh > 0; sh >>= 1) { if (t < sh) fred[t] += fred[t + sh]; __syncthreads(); }
    if (t == 0) out[0] = -(fs[127] / (float)B_SIZE) - fred[0];
}

extern "C" void kernel_launch(void* const* d_in, const int* in_sizes, int n_in,
                              void* d_out, int out_size, void* d_ws, size_t ws_size,
                              hipStream_t stream)
{
    const float* x    = (const float*)d_in[0];
    const int*   tgt  = (const int*)d_in[1];
    const float* W    = (const float*)d_in[2];
    const float* b    = (const float*)d_in[3];
    const float* beta = (const float*)d_in[4];
    const float* lp   = (const float*)d_in[5];
    float* out = (float*)d_out;

    // ws layout (floats): z partials (4 x 8192 x 256), Q (256x128), logQt (128x256),
    // Wh/Wl (u16 256x2048 each), gacc (256)
    float* z     = (float*)d_ws;
    float* Q     = z + (size_t)GKSPLIT * B_SIZE * NPAD;
    float* logQt = Q + (size_t)N_LEAF * C_SIZE;
    u16*   Wh    = (u16*)(logQt + (size_t)C_SIZE * N_LEAF);
    u16*   Wl    = Wh + (size_t)N_LEAF * D_SIZE;
    float* gacc  = (float*)(Wl + (size_t)N_LEAF * D_SIZE);

    prep_kernel<<<512, 256, 0, stream>>>(W, Wh, Wl, lp, Q, logQt, gacc);

    // flat 512-block grid; kz = bid & 3 clusters one kz per XCD under round-robin dispatch
    gemm_mfma<<<512, 256, 0, stream>>>(x, Wh, Wl, z);

    path_kernel<<<NBLK_PATH, 256, 0, stream>>>(
        z, tgt, b, beta, Q, logQt, gacc, out);

    finalize_kernel<<<1, 256, 0, stream>>>(gacc, out);
}

// Round 9
// 168.145 us; speedup vs baseline: 1.3165x; 1.3165x over previous
//
#include <hip/hip_runtime.h>
#include <hip/hip_bf16.h>
#include <hip/hip_fp16.h>
#include <stdint.h>

#define B_SIZE 8192
#define D_SIZE 2048
#define C_SIZE 128
#define N_INNER 255
#define N_LEAF 256
#define NPAD 256
#define NBLK_PATH 512

typedef _Float16 half8 __attribute__((ext_vector_type(8)));
typedef __fp16 pk16x2 __attribute__((ext_vector_type(2)));   // return type of cvt_pkrtz
typedef float f32x4 __attribute__((ext_vector_type(4)));
typedef unsigned short u16;

// ---- fp32 -> (hi,lo) fp16 split, packed pairs ----
__device__ inline uint32_t pkh(float a, float b) {
    pk16x2 h = __builtin_amdgcn_cvt_pkrtz(a, b);
    return __builtin_bit_cast(uint32_t, h);
}
__device__ inline void split4(const float4 v, uint2& hi, uint2& lo) {
    pk16x2 a01 = __builtin_amdgcn_cvt_pkrtz(v.x, v.y);
    pk16x2 a23 = __builtin_amdgcn_cvt_pkrtz(v.z, v.w);
    float r0 = v.x - (float)a01[0];
    float r1 = v.y - (float)a01[1];
    float r2 = v.z - (float)a23[0];
    float r3 = v.w - (float)a23[1];
    hi = make_uint2(__builtin_bit_cast(uint32_t, a01), __builtin_bit_cast(uint32_t, a23));
    lo = make_uint2(pkh(r0, r1), pkh(r2, r3));
}
// 8 consecutive fp32 -> hi/lo half8 fragments (same arithmetic as split4 -> bit-identical)
__device__ inline void splitB8(const float4 v0, const float4 v1, half8& h, half8& l) {
    uint2 h0, l0, h1, l1;
    split4(v0, h0, l0);
    split4(v1, h1, l1);
    uint4 hh = make_uint4(h0.x, h0.y, h1.x, h1.y);
    uint4 ll = make_uint4(l0.x, l0.y, l1.x, l1.y);
    h = __builtin_bit_cast(half8, hh);
    l = __builtin_bit_cast(half8, ll);
}

// ---------------- K-pre: softmax -> Q, logQt (W-split ELIMINATED: gemm splits B in-reg) ----------------
__global__ __launch_bounds__(256) void prep_kernel(
    const float* __restrict__ lp, float* __restrict__ Q, float* __restrict__ logQt)
{
    int row = blockIdx.x;     // 256 leaf rows
    int t = threadIdx.x;
    __shared__ float red[128];
    float v = 0.f;
    if (t < 128) { v = lp[row * C_SIZE + t]; red[t] = v; }
    __syncthreads();
    for (int s = 64; s > 0; s >>= 1) { if (t < s) red[t] = fmaxf(red[t], red[t + s]); __syncthreads(); }
    float mx = red[0]; __syncthreads();
    float e = 0.f;
    if (t < 128) { e = expf(v - mx); red[t] = e; }
    __syncthreads();
    for (int s = 64; s > 0; s >>= 1) { if (t < s) red[t] += red[t + s]; __syncthreads(); }
    float sum = red[0];
    if (t < 128) {
        Q[row * C_SIZE + t] = e / sum;
        logQt[(size_t)t * N_LEAF + row] = (v - mx) - logf(sum);   // [class][leaf]
    }
}

// ---------------- K1: z_part[kz] = x @ W^T partials, fp16-split MFMA, BARRIER-FREE ----------------
// R4 schedule FROZEN (measured 60.3 us, VGPR=128, no spill). Change vs R4: B loaded as f32
// from W directly and split hi/lo IN REGISTERS at rotate (same bytes from L2, same split
// arithmetic as the old prep pass -> bit-identical z; prep's W-split pass deleted).
// BM=64, 4 waves x 64 cols, BK=32, KSPLIT=4; A via wave-private LDS + lgkm fence; A+B
// one-deep reg prefetch; kz = bid & 3 clusters one kz per XCD (B slice L2-hot).
// NOTE: launch_bounds min-waves MUST stay 2 — (256,4) squeezed arch-VGPR to 64 and
// spilled ~1.1 GB scratch (R5: 380 us). Do not raise it.
#define GBM 64
#define GBK 32
#define GKSPLIT 4
#define KCHUNK (D_SIZE / GKSPLIT)   // 512
#define KITERS (KCHUNK / GBK)       // 16
#define LDKA 40                     // padded A row stride in u16 (80 B -> 2-way bank alias = free)

__global__ __launch_bounds__(256, 2) void gemm_mfma(
    const float* __restrict__ x, const float* __restrict__ W,
    float* __restrict__ zp)
{
    __shared__ __align__(16) u16 sAh[4][GBM * LDKA];
    __shared__ __align__(16) u16 sAl[4][GBM * LDKA];

    const int t = threadIdx.x;
    const int lane = t & 63, w = t >> 6;
    const int lr = lane & 15, lq = lane >> 4;
    const int mi = blockIdx.x >> 2;          // m-tile index 0..127
    const int kz = blockIdx.x & 3;           // kz clustered per XCD under round-robin
    const int m0 = mi * GBM;
    const int kb0 = kz * KCHUNK;

    f32x4 acc[4][4];
    #pragma unroll
    for (int mt = 0; mt < 4; ++mt)
        #pragma unroll
        for (int nt = 0; nt < 4; ++nt) acc[mt][nt] = (f32x4){0.f, 0.f, 0.f, 0.f};

    // per-lane B row indices (row 255 doesn't exist in W: clamp that single lane to 254;
    // the resulting z column 255 is provably never consumed by path_kernel)
    int brow[4];
    #pragma unroll
    for (int nt = 0; nt < 4; ++nt) {
        int rrow = w * 64 + nt * 16 + lr;
        brow[nt] = (rrow > 254) ? 254 : rrow;
    }

    // prologue: load first A tile (64 rows x 32 k fp32, 8 float4/lane, coalesced 8 lanes/row)
    float4 av_c[8];
    #pragma unroll
    for (int i = 0; i < 8; ++i) {
        int idx = i * 64 + lane;
        int row = idx >> 3, ch = idx & 7;
        av_c[i] = *(const float4*)(x + (size_t)(m0 + row) * D_SIZE + kb0 + ch * 4);
    }
    // prologue: load kt=0 B fragments (f32) and split in-register
    half8 bh[4], bl[4];
    #pragma unroll
    for (int nt = 0; nt < 4; ++nt) {
        const float* p = W + (size_t)brow[nt] * D_SIZE + kb0 + lq * 8;
        float4 b0 = *(const float4*)(p);
        float4 b1 = *(const float4*)(p + 4);
        splitB8(b0, b1, bh[nt], bl[nt]);
    }

    #pragma unroll
    for (int kt = 0; kt < KITERS; ++kt) {
        const int kb = kb0 + kt * GBK;
        // 1. issue NEXT kt's B loads (f32, consumed at rotate)
        float4 nb0[4], nb1[4];
        if (kt + 1 < KITERS) {
            #pragma unroll
            for (int nt = 0; nt < 4; ++nt) {
                const float* p = W + (size_t)brow[nt] * D_SIZE + kb + GBK + lq * 8;
                nb0[nt] = *(const float4*)(p);
                nb1[nt] = *(const float4*)(p + 4);
            }
        }
        // 2. issue NEXT kt's A loads (consumed next iteration)
        float4 av_n[8];
        if (kt + 1 < KITERS) {
            #pragma unroll
            for (int i = 0; i < 8; ++i) {
                int idx = i * 64 + lane;
                int row = idx >> 3, ch = idx & 7;
                av_n[i] = *(const float4*)(x + (size_t)(m0 + row) * D_SIZE + kb + GBK + ch * 4);
            }
        }
        // 3. split current A into this wave's private LDS region
        #pragma unroll
        for (int i = 0; i < 8; ++i) {
            int idx = i * 64 + lane;
            int row = idx >> 3, ch = idx & 7;
            uint2 hi, lo; split4(av_c[i], hi, lo);
            *(uint2*)&sAh[w][row * LDKA + ch * 4] = hi;
            *(uint2*)&sAl[w][row * LDKA + ch * 4] = lo;
        }
        asm volatile("s_waitcnt lgkmcnt(0)" ::: "memory");  // wave-sync LDS: writes visible to own wave
        // 4. A fragments
        half8 ah[4], al[4];
        #pragma unroll
        for (int mt = 0; mt < 4; ++mt) {
            int off = (mt * 16 + lr) * LDKA + lq * 8;
            ah[mt] = *(const half8*)&sAh[w][off];
            al[mt] = *(const half8*)&sAl[w][off];
        }
        // 5. MFMA (hi*hi + hi*lo + lo*hi)
        #pragma unroll
        for (int mt = 0; mt < 4; ++mt)
            #pragma unroll
            for (int nt = 0; nt < 4; ++nt) {
                acc[mt][nt] = __builtin_amdgcn_mfma_f32_16x16x32_f16(ah[mt], bh[nt], acc[mt][nt], 0, 0, 0);
                acc[mt][nt] = __builtin_amdgcn_mfma_f32_16x16x32_f16(ah[mt], bl[nt], acc[mt][nt], 0, 0, 0);
                acc[mt][nt] = __builtin_amdgcn_mfma_f32_16x16x32_f16(al[mt], bh[nt], acc[mt][nt], 0, 0, 0);
            }
        // 6. rotate prefetched A; split prefetched B f32 -> hi/lo fragments
        if (kt + 1 < KITERS) {
            #pragma unroll
            for (int i = 0; i < 8; ++i) av_c[i] = av_n[i];
            #pragma unroll
            for (int nt = 0; nt < 4; ++nt) splitB8(nb0[nt], nb1[nt], bh[nt], bl[nt]);
        }
    }

    float* zout = zp + (size_t)kz * B_SIZE * NPAD;
    #pragma unroll
    for (int mt = 0; mt < 4; ++mt) {
        #pragma unroll
        for (int nt = 0; nt < 4; ++nt) {
            int gn = w * 64 + nt * 16 + lr;
            #pragma unroll
            for (int r = 0; r < 4; ++r) {
                int gm = m0 + mt * 16 + lq * 4 + r;
                zout[(size_t)gm * NPAD + gn] = acc[mt][nt][r];
            }
        }
    }
}

// ---------------- K2: fused reduce + sigmoid + paths + penalties + loss + argmax gather ----------------
// R4 shape (best measured total): 512 blocks x 4 waves x 4 rows, partial-record write,
// NO global atomics/fences. Factored tree walk from R7 (measured 60.6, bit-identical order).
__global__ __launch_bounds__(256) void path_kernel(
    const float* __restrict__ z, const int* __restrict__ target,
    const float* __restrict__ bvec, const float* __restrict__ beta,
    const float* __restrict__ Q, const float* __restrict__ logQt,
    float* __restrict__ partial, float* __restrict__ out)
{
    __shared__ float pbuf[4][256];
    __shared__ float s_num[128], s_den[128], s_loss;
    const int t = threadIdx.x, w = t >> 6, lane = t & 63;
    const int c0 = lane * 4;
    float pnum[4] = {0.f, 0.f, 0.f, 0.f};
    float pden[4] = {0.f, 0.f, 0.f, 0.f};
    float loss = 0.f;

    if (t < 128) s_num[t] = 0.f;
    else s_den[t - 128] = 0.f;
    if (t == 0) s_loss = 0.f;
    __syncthreads();   // init visible to all waves before end-of-kernel atomics

    float bet[4], bia[4];
    #pragma unroll
    for (int j = 0; j < 4; ++j) {
        int c = c0 + j;
        bet[j] = (c < N_INNER) ? beta[c] : 0.f;
        bia[j] = (c < N_INNER) ? bvec[c] : 0.f;
    }

    for (int i = 0; i < 4; ++i) {
        int r = blockIdx.x * 16 + w * 4 + i;
        float4 s = make_float4(0.f, 0.f, 0.f, 0.f);
        #pragma unroll
        for (int p = 0; p < GKSPLIT; ++p) {
            float4 v = *(const float4*)(z + ((size_t)p * B_SIZE + r) * NPAD + c0);
            s.x += v.x; s.y += v.y; s.z += v.z; s.w += v.w;
        }
        float zv[4] = {s.x, s.y, s.z, s.w};
        float pv[4];
        #pragma unroll
        for (int j = 0; j < 4; ++j) {
            int c = c0 + j;
            pv[j] = (c < N_INNER) ? 1.f / (1.f + expf(-bet[j] * (zv[j] + bia[j]))) : 0.f;
        }
        *(float4*)&pbuf[w][c0] = make_float4(pv[0], pv[1], pv[2], pv[3]);
        asm volatile("s_waitcnt lgkmcnt(0)" ::: "memory");  // wave-private LDS visibility

        int tg = target[r];
        float4 lq4 = *(const float4*)(logQt + (size_t)tg * N_LEAF + c0);
        float lqa[4] = {lq4.x, lq4.y, lq4.z, lq4.w};

        // ---- leaf path products, factored (bit-identical association order):
        // leaves c0..c0+3 share levels d=0..5; d=6 node common (bit = j>>1);
        // d=7 node = 127 + 2*lane + (j>>1), bit = j&1.
        float P = 1.f;
        #pragma unroll
        for (int d = 0; d < 6; ++d) {
            int node = (1 << d) - 1 + (c0 >> (8 - d));
            int bit = (c0 >> (7 - d)) & 1;
            float pvn = pbuf[w][node];
            P *= bit ? pvn : (1.f - pvn);
        }
        float p6  = pbuf[w][63 + lane];
        float p7a = pbuf[w][127 + 2 * lane];
        float p7b = pbuf[w][127 + 2 * lane + 1];
        float lsum = 0.f, bestV = -1.f;
        int bestI = 0;
        #pragma unroll
        for (int j = 0; j < 4; ++j) {
            float t6 = (j & 2) ? p6 : (1.f - p6);
            float p7 = (j & 2) ? p7b : p7a;
            float t7 = (j & 1) ? p7 : (1.f - p7);
            float pl = (P * t6) * t7;
            lsum += pl * lqa[j];
            if (pl > bestV) { bestV = pl; bestI = c0 + j; }  // ascending j keeps lowest tie
        }
        if (lane < 32) {
            #pragma unroll
            for (int j = 0; j < 4; ++j) {
                int c = c0 + j;
                if (c < 127) {
                    int h = c + 1; int d = 31 - __clz(h);
                    float pp = 1.f;
                    for (int e = 0; e < d; ++e) {
                        int ha = h >> (d - e);
                        int bit = (h >> (d - 1 - e)) & 1;
                        float pvn = pbuf[w][ha - 1];
                        pp *= bit ? pvn : (1.f - pvn);
                    }
                    pnum[j] += pbuf[w][c] * pp;
                    pden[j] += pp;
                }
            }
        }
        #pragma unroll
        for (int m = 1; m < 64; m <<= 1) {
            lsum += __shfl_xor(lsum, m, 64);
            float ov = __shfl_xor(bestV, m, 64);
            int   oi = __shfl_xor(bestI, m, 64);
            if (ov > bestV || (ov == bestV && oi < bestI)) { bestV = ov; bestI = oi; }
        }
        loss += lsum;
        out[1 + (size_t)r * C_SIZE + lane]      = Q[bestI * C_SIZE + lane];
        out[1 + (size_t)r * C_SIZE + lane + 64] = Q[bestI * C_SIZE + lane + 64];
        asm volatile("" ::: "memory");  // keep next iter's pbuf write after this iter's reads
    }

    // block-level reduction via LDS atomics, then one global store per thread
    if (lane < 32) {
        #pragma unroll
        for (int j = 0; j < 4; ++j) {
            int c = c0 + j;
            if (c < 127) {
                atomicAdd(&s_num[c], pnum[j]);
                atomicAdd(&s_den[c], pden[j]);
            }
        }
    }
    if (lane == 0) atomicAdd(&s_loss, loss);
    __syncthreads();
    float* rec = partial + (size_t)blockIdx.x * 256;
    if (t < 127)        rec[t] = s_num[t];
    else if (t == 127)  rec[127] = s_loss;
    else if (t < 255)   rec[t] = s_den[t - 128];
    else                rec[255] = 0.f;
}

// ---------------- K3: reduce partials + finalize total (1024 threads: 4x parallel) ----------------
__global__ __launch_bounds__(1024) void reduce_kernel(
    const float* __restrict__ partial, float* __restrict__ out)
{
    __shared__ float part[4][256];
    __shared__ float s[256];
    __shared__ float red[128];
    const int t = threadIdx.x;
    const int col = t & 255, seg = t >> 8;           // 4 segments of 128 records
    const int base = seg * (NBLK_PATH / 4);
    float a0 = 0.f, a1 = 0.f, a2 = 0.f, a3 = 0.f;
    for (int r = 0; r < NBLK_PATH / 4; r += 4) {
        a0 += partial[(size_t)(base + r + 0) * 256 + col];
        a1 += partial[(size_t)(base + r + 1) * 256 + col];
        a2 += partial[(size_t)(base + r + 2) * 256 + col];
        a3 += partial[(size_t)(base + r + 3) * 256 + col];
    }
    part[seg][col] = (a0 + a1) + (a2 + a3);
    __syncthreads();
    if (t < 256) s[t] = (part[0][t] + part[1][t]) + (part[2][t] + part[3][t]);
    __syncthreads();
    float term = 0.f;
    if (t < 127) {
        int d = 31 - __clz(t + 1);
        float lam = 0.1f * exp2f(-(float)(d + 1));
        float pen = s[t] / s[128 + t];
        term = lam * 0.5f * (logf(pen) + logf(1.f - pen));
    }
    if (t < 128) { red[t] = term; }
    __syncthreads();
    for (int sh = 64; sh > 0; sh >>= 1) { if (t < sh) red[t] += red[t + sh]; __syncthreads(); }
    if (t == 0) out[0] = -(s[127] / (float)B_SIZE) - red[0];
}

extern "C" void kernel_launch(void* const* d_in, const int* in_sizes, int n_in,
                              void* d_out, int out_size, void* d_ws, size_t ws_size,
                              hipStream_t stream)
{
    const float* x    = (const float*)d_in[0];
    const int*   tgt  = (const int*)d_in[1];
    const float* W    = (const float*)d_in[2];
    const float* b    = (const float*)d_in[3];
    const float* beta = (const float*)d_in[4];
    const float* lp   = (const float*)d_in[5];
    float* out = (float*)d_out;

    // ws layout (floats): z partials (4 x 8192 x 256), Q (256x128), logQt (128x256),
    // block partials (512 x 256)
    float* z       = (float*)d_ws;
    float* Q       = z + (size_t)GKSPLIT * B_SIZE * NPAD;
    float* logQt   = Q + (size_t)N_LEAF * C_SIZE;
    float* partial = logQt + (size_t)C_SIZE * N_LEAF;

    prep_kernel<<<256, 256, 0, stream>>>(lp, Q, logQt);

    // flat 512-block grid; kz = bid & 3 clusters one kz per XCD under round-robin dispatch
    gemm_mfma<<<512, 256, 0, stream>>>(x, W, z);

    path_kernel<<<NBLK_PATH, 256, 0, stream>>>(
        z, tgt, b, beta, Q, logQt, partial, out);

    reduce_kernel<<<1, 1024, 0, stream>>>(partial, out);
}

// Round 10
// 166.701 us; speedup vs baseline: 1.3279x; 1.0087x over previous
//
#include <hip/hip_runtime.h>
#include <hip/hip_bf16.h>
#include <hip/hip_fp16.h>
#include <stdint.h>

#define B_SIZE 8192
#define D_SIZE 2048
#define C_SIZE 128
#define N_INNER 255
#define N_LEAF 256
#define NPAD 256
#define NBLK_PATH 512

typedef _Float16 half8 __attribute__((ext_vector_type(8)));
typedef __fp16 pk16x2 __attribute__((ext_vector_type(2)));   // return type of cvt_pkrtz
typedef float f32x4 __attribute__((ext_vector_type(4)));
typedef unsigned short u16;

// ---- fp32 -> (hi,lo) fp16 split, packed pairs ----
__device__ inline uint32_t pkh(float a, float b) {
    pk16x2 h = __builtin_amdgcn_cvt_pkrtz(a, b);
    return __builtin_bit_cast(uint32_t, h);
}
__device__ inline void split4(const float4 v, uint2& hi, uint2& lo) {
    pk16x2 a01 = __builtin_amdgcn_cvt_pkrtz(v.x, v.y);
    pk16x2 a23 = __builtin_amdgcn_cvt_pkrtz(v.z, v.w);
    float r0 = v.x - (float)a01[0];
    float r1 = v.y - (float)a01[1];
    float r2 = v.z - (float)a23[0];
    float r3 = v.w - (float)a23[1];
    hi = make_uint2(__builtin_bit_cast(uint32_t, a01), __builtin_bit_cast(uint32_t, a23));
    lo = make_uint2(pkh(r0, r1), pkh(r2, r3));
}
// 8 consecutive fp32 -> hi/lo half8 fragments (same arithmetic as split4 -> bit-identical)
__device__ inline void splitB8(const float4 v0, const float4 v1, half8& h, half8& l) {
    uint2 h0, l0, h1, l1;
    split4(v0, h0, l0);
    split4(v1, h1, l1);
    uint4 hh = make_uint4(h0.x, h0.y, h1.x, h1.y);
    uint4 ll = make_uint4(l0.x, l0.y, l1.x, l1.y);
    h = __builtin_bit_cast(half8, hh);
    l = __builtin_bit_cast(half8, ll);
}

// ---------------- K1 (merged): gemm tiles (bid<512) + leaf softmax (bid>=512) ----------------
// gemm no longer depends on prep output (R9: B split in-register), so the softmax pass
// rides in the same launch as blocks 512..767 -> one fewer serialized dispatch.
// gemm schedule FROZEN at R9's measured 54.5 us config: BM=64, 4 waves x 64 cols, BK=32,
// KSPLIT=4; A via wave-private LDS + lgkm fence; A+B one-deep reg prefetch; B loaded f32
// and split hi/lo at rotate (bit-identical to the old prep split); kz = bid & 3 clusters
// one kz per XCD under round-robin dispatch.
// NOTE: launch_bounds min-waves MUST stay 2 — (256,4) squeezed arch-VGPR to 64 and
// spilled ~1.1 GB scratch (R5: 380 us). Do not raise it.
#define GBM 64
#define GBK 32
#define GKSPLIT 4
#define KCHUNK (D_SIZE / GKSPLIT)   // 512
#define KITERS (KCHUNK / GBK)       // 16
#define LDKA 40                     // padded A row stride in u16 (80 B -> 2-way bank alias = free)

__global__ __launch_bounds__(256, 2) void gemm_prep(
    const float* __restrict__ x, const float* __restrict__ W, float* __restrict__ zp,
    const float* __restrict__ lp, float* __restrict__ Q, float* __restrict__ logQt)
{
    __shared__ __align__(16) u16 sAh[4][GBM * LDKA];
    __shared__ __align__(16) u16 sAl[4][GBM * LDKA];
    __shared__ float red[128];

    const int t = threadIdx.x;

    if (blockIdx.x >= 512) {
        // ---- softmax over leaf row (block-uniform branch) ----
        int row = blockIdx.x - 512;
        float v = 0.f;
        if (t < 128) { v = lp[row * C_SIZE + t]; red[t] = v; }
        __syncthreads();
        for (int s = 64; s > 0; s >>= 1) { if (t < s) red[t] = fmaxf(red[t], red[t + s]); __syncthreads(); }
        float mx = red[0]; __syncthreads();
        float e = 0.f;
        if (t < 128) { e = expf(v - mx); red[t] = e; }
        __syncthreads();
        for (int s = 64; s > 0; s >>= 1) { if (t < s) red[t] += red[t + s]; __syncthreads(); }
        float sum = red[0];
        if (t < 128) {
            Q[row * C_SIZE + t] = e / sum;
            logQt[(size_t)t * N_LEAF + row] = (v - mx) - logf(sum);   // [class][leaf]
        }
        return;
    }

    const int lane = t & 63, w = t >> 6;
    const int lr = lane & 15, lq = lane >> 4;
    const int mi = blockIdx.x >> 2;          // m-tile index 0..127
    const int kz = blockIdx.x & 3;           // kz clustered per XCD under round-robin
    const int m0 = mi * GBM;
    const int kb0 = kz * KCHUNK;

    f32x4 acc[4][4];
    #pragma unroll
    for (int mt = 0; mt < 4; ++mt)
        #pragma unroll
        for (int nt = 0; nt < 4; ++nt) acc[mt][nt] = (f32x4){0.f, 0.f, 0.f, 0.f};

    // per-lane B row indices (row 255 doesn't exist in W: clamp that single lane to 254;
    // the resulting z column 255 is provably never consumed by path_kernel)
    int brow[4];
    #pragma unroll
    for (int nt = 0; nt < 4; ++nt) {
        int rrow = w * 64 + nt * 16 + lr;
        brow[nt] = (rrow > 254) ? 254 : rrow;
    }

    // prologue: load first A tile (64 rows x 32 k fp32, 8 float4/lane, coalesced 8 lanes/row)
    float4 av_c[8];
    #pragma unroll
    for (int i = 0; i < 8; ++i) {
        int idx = i * 64 + lane;
        int row = idx >> 3, ch = idx & 7;
        av_c[i] = *(const float4*)(x + (size_t)(m0 + row) * D_SIZE + kb0 + ch * 4);
    }
    // prologue: load kt=0 B fragments (f32) and split in-register
    half8 bh[4], bl[4];
    #pragma unroll
    for (int nt = 0; nt < 4; ++nt) {
        const float* p = W + (size_t)brow[nt] * D_SIZE + kb0 + lq * 8;
        float4 b0 = *(const float4*)(p);
        float4 b1 = *(const float4*)(p + 4);
        splitB8(b0, b1, bh[nt], bl[nt]);
    }

    #pragma unroll
    for (int kt = 0; kt < KITERS; ++kt) {
        const int kb = kb0 + kt * GBK;
        // 1. issue NEXT kt's B loads (f32, consumed at rotate)
        float4 nb0[4], nb1[4];
        if (kt + 1 < KITERS) {
            #pragma unroll
            for (int nt = 0; nt < 4; ++nt) {
                const float* p = W + (size_t)brow[nt] * D_SIZE + kb + GBK + lq * 8;
                nb0[nt] = *(const float4*)(p);
                nb1[nt] = *(const float4*)(p + 4);
            }
        }
        // 2. issue NEXT kt's A loads (consumed next iteration)
        float4 av_n[8];
        if (kt + 1 < KITERS) {
            #pragma unroll
            for (int i = 0; i < 8; ++i) {
                int idx = i * 64 + lane;
                int row = idx >> 3, ch = idx & 7;
                av_n[i] = *(const float4*)(x + (size_t)(m0 + row) * D_SIZE + kb + GBK + ch * 4);
            }
        }
        // 3. split current A into this wave's private LDS region
        #pragma unroll
        for (int i = 0; i < 8; ++i) {
            int idx = i * 64 + lane;
            int row = idx >> 3, ch = idx & 7;
            uint2 hi, lo; split4(av_c[i], hi, lo);
            *(uint2*)&sAh[w][row * LDKA + ch * 4] = hi;
            *(uint2*)&sAl[w][row * LDKA + ch * 4] = lo;
        }
        asm volatile("s_waitcnt lgkmcnt(0)" ::: "memory");  // wave-sync LDS: writes visible to own wave
        // 4. A fragments
        half8 ah[4], al[4];
        #pragma unroll
        for (int mt = 0; mt < 4; ++mt) {
            int off = (mt * 16 + lr) * LDKA + lq * 8;
            ah[mt] = *(const half8*)&sAh[w][off];
            al[mt] = *(const half8*)&sAl[w][off];
        }
        // 5. MFMA (hi*hi + hi*lo + lo*hi)
        #pragma unroll
        for (int mt = 0; mt < 4; ++mt)
            #pragma unroll
            for (int nt = 0; nt < 4; ++nt) {
                acc[mt][nt] = __builtin_amdgcn_mfma_f32_16x16x32_f16(ah[mt], bh[nt], acc[mt][nt], 0, 0, 0);
                acc[mt][nt] = __builtin_amdgcn_mfma_f32_16x16x32_f16(ah[mt], bl[nt], acc[mt][nt], 0, 0, 0);
                acc[mt][nt] = __builtin_amdgcn_mfma_f32_16x16x32_f16(al[mt], bh[nt], acc[mt][nt], 0, 0, 0);
            }
        // 6. rotate prefetched A; split prefetched B f32 -> hi/lo fragments
        if (kt + 1 < KITERS) {
            #pragma unroll
            for (int i = 0; i < 8; ++i) av_c[i] = av_n[i];
            #pragma unroll
            for (int nt = 0; nt < 4; ++nt) splitB8(nb0[nt], nb1[nt], bh[nt], bl[nt]);
        }
    }

    float* zout = zp + (size_t)kz * B_SIZE * NPAD;
    #pragma unroll
    for (int mt = 0; mt < 4; ++mt) {
        #pragma unroll
        for (int nt = 0; nt < 4; ++nt) {
            int gn = w * 64 + nt * 16 + lr;
            #pragma unroll
            for (int r = 0; r < 4; ++r) {
                int gm = m0 + mt * 16 + lq * 4 + r;
                zout[(size_t)gm * NPAD + gn] = acc[mt][nt][r];
            }
        }
    }
}

// ---------------- K2: fused reduce + sigmoid + paths + penalties + loss + argmax gather ----------------
// 512 blocks x 4 waves x 4 rows, BUT the 4 rows are now PIPELINED, not serial:
// each row gets its own pbuf slice (pbuf[16][256], 16 KB), all 16 z-float4 loads + 4
// target/logQt rows issued up front, ONE lgkm fence, then 4 back-to-back tree walks.
// Collapses 4 serialized HBM round trips per wave into one. Summation order (i ascending)
// identical to R9 -> bit-identical results. No global atomics/fences (R8 lesson).
__global__ __launch_bounds__(256) void path_kernel(
    const float* __restrict__ z, const int* __restrict__ target,
    const float* __restrict__ bvec, const float* __restrict__ beta,
    const float* __restrict__ Q, const float* __restrict__ logQt,
    float* __restrict__ partial, float* __restrict__ out)
{
    __shared__ float pbuf[16][256];     // [w*4 + i]
    __shared__ float s_num[128], s_den[128], s_loss;
    const int t = threadIdx.x, w = t >> 6, lane = t & 63;
    const int c0 = lane * 4;
    float pnum[4] = {0.f, 0.f, 0.f, 0.f};
    float pden[4] = {0.f, 0.f, 0.f, 0.f};
    float loss = 0.f;

    if (t < 128) s_num[t] = 0.f;
    else s_den[t - 128] = 0.f;
    if (t == 0) s_loss = 0.f;
    __syncthreads();   // init visible to all waves before end-of-kernel atomics

    float bet[4], bia[4];
    #pragma unroll
    for (int j = 0; j < 4; ++j) {
        int c = c0 + j;
        bet[j] = (c < N_INNER) ? beta[c] : 0.f;
        bia[j] = (c < N_INNER) ? bvec[c] : 0.f;
    }

    const int rbase = blockIdx.x * 16 + w * 4;

    // ---- phase 1: all 4 rows' z partials (16 independent float4 loads), reduce ----
    float4 zs[4];
    #pragma unroll
    for (int i = 0; i < 4; ++i) {
        float4 s = make_float4(0.f, 0.f, 0.f, 0.f);
        #pragma unroll
        for (int p = 0; p < GKSPLIT; ++p) {
            float4 v = *(const float4*)(z + ((size_t)p * B_SIZE + rbase + i) * NPAD + c0);
            s.x += v.x; s.y += v.y; s.z += v.z; s.w += v.w;
        }
        zs[i] = s;
    }
    int tg[4];
    #pragma unroll
    for (int i = 0; i < 4; ++i) tg[i] = target[rbase + i];

    // sigmoid all 4 rows, store each to its own pbuf slice
    #pragma unroll
    for (int i = 0; i < 4; ++i) {
        float zv[4] = {zs[i].x, zs[i].y, zs[i].z, zs[i].w};
        float pv[4];
        #pragma unroll
        for (int j = 0; j < 4; ++j) {
            int c = c0 + j;
            pv[j] = (c < N_INNER) ? 1.f / (1.f + expf(-bet[j] * (zv[j] + bia[j]))) : 0.f;
        }
        *(float4*)&pbuf[w * 4 + i][c0] = make_float4(pv[0], pv[1], pv[2], pv[3]);
    }
    float4 lq[4];
    #pragma unroll
    for (int i = 0; i < 4; ++i)
        lq[i] = *(const float4*)(logQt + (size_t)tg[i] * N_LEAF + c0);
    asm volatile("s_waitcnt lgkmcnt(0)" ::: "memory");  // wave-private LDS: one fence for all slices

    // ---- phase 2: 4 back-to-back tree walks (all data now in LDS/regs) ----
    #pragma unroll
    for (int i = 0; i < 4; ++i) {
        const float* pb = pbuf[w * 4 + i];
        const int r = rbase + i;
        float lqa[4] = {lq[i].x, lq[i].y, lq[i].z, lq[i].w};

        // leaf path products, factored (bit-identical association order):
        // leaves c0..c0+3 share levels d=0..5; d=6 node common (bit = j>>1);
        // d=7 node = 127 + 2*lane + (j>>1), bit = j&1.
        float P = 1.f;
        #pragma unroll
        for (int d = 0; d < 6; ++d) {
            int node = (1 << d) - 1 + (c0 >> (8 - d));
            int bit = (c0 >> (7 - d)) & 1;
            float pvn = pb[node];
            P *= bit ? pvn : (1.f - pvn);
        }
        float p6  = pb[63 + lane];
        float p7a = pb[127 + 2 * lane];
        float p7b = pb[127 + 2 * lane + 1];
        float lsum = 0.f, bestV = -1.f;
        int bestI = 0;
        #pragma unroll
        for (int j = 0; j < 4; ++j) {
            float t6 = (j & 2) ? p6 : (1.f - p6);
            float p7 = (j & 2) ? p7b : p7a;
            float t7 = (j & 1) ? p7 : (1.f - p7);
            float pl = (P * t6) * t7;
            lsum += pl * lqa[j];
            if (pl > bestV) { bestV = pl; bestI = c0 + j; }  // ascending j keeps lowest tie
        }
        if (lane < 32) {
            #pragma unroll
            for (int j = 0; j < 4; ++j) {
                int c = c0 + j;
                if (c < 127) {
                    int h = c + 1; int d = 31 - __clz(h);
                    float pp = 1.f;
                    for (int e = 0; e < d; ++e) {
                        int ha = h >> (d - e);
                        int bit = (h >> (d - 1 - e)) & 1;
                        float pvn = pb[ha - 1];
                        pp *= bit ? pvn : (1.f - pvn);
                    }
                    pnum[j] += pb[c] * pp;
                    pden[j] += pp;
                }
            }
        }
        #pragma unroll
        for (int m = 1; m < 64; m <<= 1) {
            lsum += __shfl_xor(lsum, m, 64);
            float ov = __shfl_xor(bestV, m, 64);
            int   oi = __shfl_xor(bestI, m, 64);
            if (ov > bestV || (ov == bestV && oi < bestI)) { bestV = ov; bestI = oi; }
        }
        loss += lsum;
        out[1 + (size_t)r * C_SIZE + lane]      = Q[bestI * C_SIZE + lane];
        out[1 + (size_t)r * C_SIZE + lane + 64] = Q[bestI * C_SIZE + lane + 64];
    }

    // block-level reduction via LDS atomics, then one global store per thread
    if (lane < 32) {
        #pragma unroll
        for (int j = 0; j < 4; ++j) {
            int c = c0 + j;
            if (c < 127) {
                atomicAdd(&s_num[c], pnum[j]);
                atomicAdd(&s_den[c], pden[j]);
            }
        }
    }
    if (lane == 0) atomicAdd(&s_loss, loss);
    __syncthreads();
    float* rec = partial + (size_t)blockIdx.x * 256;
    if (t < 127)        rec[t] = s_num[t];
    else if (t == 127)  rec[127] = s_loss;
    else if (t < 255)   rec[t] = s_den[t - 128];
    else                rec[255] = 0.f;
}

// ---------------- K3: reduce partials + finalize total (1024 threads: 4x parallel) ----------------
__global__ __launch_bounds__(1024) void reduce_kernel(
    const float* __restrict__ partial, float* __restrict__ out)
{
    __shared__ float part[4][256];
    __shared__ float s[256];
    __shared__ float red[128];
    const int t = threadIdx.x;
    const int col = t & 255, seg = t >> 8;           // 4 segments of 128 records
    const int base = seg * (NBLK_PATH / 4);
    float a0 = 0.f, a1 = 0.f, a2 = 0.f, a3 = 0.f;
    for (int r = 0; r < NBLK_PATH / 4; r += 4) {
        a0 += partial[(size_t)(base + r + 0) * 256 + col];
        a1 += partial[(size_t)(base + r + 1) * 256 + col];
        a2 += partial[(size_t)(base + r + 2) * 256 + col];
        a3 += partial[(size_t)(base + r + 3) * 256 + col];
    }
    part[seg][col] = (a0 + a1) + (a2 + a3);
    __syncthreads();
    if (t < 256) s[t] = (part[0][t] + part[1][t]) + (part[2][t] + part[3][t]);
    __syncthreads();
    float term = 0.f;
    if (t < 127) {
        int d = 31 - __clz(t + 1);
        float lam = 0.1f * exp2f(-(float)(d + 1));
        float pen = s[t] / s[128 + t];
        term = lam * 0.5f * (logf(pen) + logf(1.f - pen));
    }
    if (t < 128) { red[t] = term; }
    __syncthreads();
    for (int sh = 64; sh > 0; sh >>= 1) { if (t < sh) red[t] += red[t + sh]; __syncthreads(); }
    if (t == 0) out[0] = -(s[127] / (float)B_SIZE) - red[0];
}

extern "C" void kernel_launch(void* const* d_in, const int* in_sizes, int n_in,
                              void* d_out, int out_size, void* d_ws, size_t ws_size,
                              hipStream_t stream)
{
    const float* x    = (const float*)d_in[0];
    const int*   tgt  = (const int*)d_in[1];
    const float* W    = (const float*)d_in[2];
    const float* b    = (const float*)d_in[3];
    const float* beta = (const float*)d_in[4];
    const float* lp   = (const float*)d_in[5];
    float* out = (float*)d_out;

    // ws layout (floats): z partials (4 x 8192 x 256), Q (256x128), logQt (128x256),
    // block partials (512 x 256)
    float* z       = (float*)d_ws;
    float* Q       = z + (size_t)GKSPLIT * B_SIZE * NPAD;
    float* logQt   = Q + (size_t)N_LEAF * C_SIZE;
    float* partial = logQt + (size_t)C_SIZE * N_LEAF;

    // merged launch: blocks 0..511 gemm tiles (kz = bid & 3 XCD clustering),
    // blocks 512..767 leaf softmax
    gemm_prep<<<768, 256, 0, stream>>>(x, W, z, lp, Q, logQt);

    path_kernel<<<NBLK_PATH, 256, 0, stream>>>(
        z, tgt, b, beta, Q, logQt, partial, out);

    reduce_kernel<<<1, 1024, 0, stream>>>(partial, out);
}